// Round 2
// baseline (346.029 us; speedup 1.0000x reference)
//
#include <hip/hip_runtime.h>
#include <hip/hip_bf16.h>

// out = relu(x @ W1 + b1) @ W2 + b2
// W1 (500x50) and W2 (50x2) are precontracted from the MPO cores each call.

#define R 10

// ---------------- build kernel: contract MPO chains into dense W1, W2 ----
__global__ void build_w_kernel(const float* __restrict__ A1, const float* __restrict__ A2,
                               const float* __restrict__ A3, const float* __restrict__ A4,
                               const float* __restrict__ A5,
                               const float* __restrict__ B1, const float* __restrict__ B2,
                               const float* __restrict__ B3,
                               float* __restrict__ W1, float* __restrict__ W2) {
    // A1:(2,10,1) A2:(10,5,10,5) A3:(10,5,10,5) A4:(10,5,10,2) A5:(10,2,1)
    // W1[f][o], f=(((i*5+j)*5+k)*5+l)*2+m, o=(v*5+w)*2+x
    // W1 = sum_{p,q,r,s} A1[i,p] A2[p,j,q,v] A3[q,k,r,w] A4[r,l,s,x] A5[s,m]
    __shared__ float C45[200];    // ((r*5+l)*2+m)*2+x
    __shared__ float C345[5000];  // ((((q*5+k)*5+l)*2+m)*5+w)*2+x
    __shared__ float L2c[500];    // ((i*5+j)*10+q)*5+v
    const int tid = threadIdx.x;

    // C45[r][l][m][x] = sum_s A4[((r*5+l)*10+s)*2+x] * A5[s*2+m]
    for (int t = tid; t < 200; t += 256) {
        int x_ = t & 1, m = (t >> 1) & 1, l = (t >> 2) % 5, r = t / 20;
        float s = 0.f;
        for (int ss = 0; ss < R; ++ss)
            s += A4[((r * 5 + l) * R + ss) * 2 + x_] * A5[ss * 2 + m];
        C45[t] = s;
    }
    // L2c[i][j][q][v] = sum_p A1[i*10+p] * A2[((p*5+j)*10+q)*5+v]
    for (int t = tid; t < 500; t += 256) {
        int v = t % 5, q = (t / 5) % R, j = (t / 50) % 5, i = t / 250;
        float s = 0.f;
        for (int p = 0; p < R; ++p)
            s += A1[i * R + p] * A2[((p * 5 + j) * R + q) * 5 + v];
        L2c[t] = s;
    }
    __syncthreads();
    // C345[q][k][l][m][w][x] = sum_r A3[((q*5+k)*10+r)*5+w] * C45[((r*5+l)*2+m)*2+x]
    for (int t = tid; t < 5000; t += 256) {
        int x_ = t % 2, w = (t / 2) % 5, m = (t / 10) % 2, l = (t / 20) % 5,
            k = (t / 100) % 5, q = t / 500;
        float s = 0.f;
        for (int r = 0; r < R; ++r)
            s += A3[((q * 5 + k) * R + r) * 5 + w] * C45[((r * 5 + l) * 2 + m) * 2 + x_];
        C345[t] = s;
    }
    __syncthreads();
    // W1[f*50+o] = sum_q L2c[((i*5+j)*10+q)*5+v] * C345[((((q*5+k)*5+l)*2+m)*5+w)*2+x]
    for (int t = tid; t < 25000; t += 256) {
        int o = t % 50, f = t / 50;
        int x_ = o % 2, w = (o / 2) % 5, v = o / 10;
        int m = f % 2, l = (f / 2) % 5, k = (f / 10) % 5, j = (f / 50) % 5, i = f / 250;
        float s = 0.f;
        for (int q = 0; q < R; ++q)
            s += L2c[((i * 5 + j) * R + q) * 5 + v] *
                 C345[((((q * 5 + k) * 5 + l) * 2 + m) * 5 + w) * 2 + x_];
        W1[t] = s;
    }
    // W2[f2*2+v] = sum_{p,q} B1[i*10+p] * B2[((p*5+j)*10+q)*2+v] * B3[q*5+k]
    for (int t = tid; t < 100; t += 256) {
        int v = t % 2, f2 = t / 2;
        int k = f2 % 5, j = (f2 / 5) % 5, i = f2 / 25;
        float s = 0.f;
        for (int p = 0; p < R; ++p) {
            float bp = B1[i * R + p];
            for (int q = 0; q < R; ++q)
                s += bp * B2[((p * 5 + j) * R + q) * 2 + v] * B3[q * 5 + k];
        }
        W2[t] = s;
    }
}

// ---------------- main kernel: out = relu(x@W1+b1)@W2 + b2 ----------------
#define KC 100       // k-chunk staged in LDS
#define NCHUNK 5     // 500 / KC

__global__ __launch_bounds__(256) void tn_mlp_kernel(
    const float* __restrict__ x, const float* __restrict__ W1g,
    const float* __restrict__ W2g, const float* __restrict__ b1,
    const float* __restrict__ b2, float* __restrict__ out) {
    __shared__ float Ws[KC * 50];   // 20 KB
    __shared__ float W2s[100];
    __shared__ float b1s[50];

    const int tid = threadIdx.x;
    const int row = blockIdx.x * 256 + tid;

    if (tid < 100) W2s[tid] = W2g[tid];
    if (tid < 50) b1s[tid] = b1[tid];

    float acc[50];
#pragma unroll
    for (int j = 0; j < 50; ++j) acc[j] = 0.f;

    const float4* __restrict__ xr = (const float4*)(x + (long)row * 500);

    for (int c = 0; c < NCHUNK; ++c) {
        __syncthreads();  // previous chunk fully consumed
        for (int t = tid; t < KC * 50; t += 256) Ws[t] = W1g[c * (KC * 50) + t];
        __syncthreads();
#pragma unroll 1
        for (int k4 = 0; k4 < KC / 4; ++k4) {
            float4 xv = xr[c * (KC / 4) + k4];
            const float* wp = &Ws[(k4 * 4) * 50];
#pragma unroll
            for (int kk = 0; kk < 4; ++kk) {
                float xs = (kk == 0) ? xv.x : (kk == 1) ? xv.y : (kk == 2) ? xv.z : xv.w;
#pragma unroll
                for (int j = 0; j < 50; ++j)
                    acc[j] = fmaf(xs, wp[kk * 50 + j], acc[j]);
            }
        }
    }

    float o0 = b2[0], o1 = b2[1];
#pragma unroll
    for (int j = 0; j < 50; ++j) {
        float h = acc[j] + b1s[j];
        h = fmaxf(h, 0.f);
        o0 = fmaf(h, W2s[j * 2 + 0], o0);
        o1 = fmaf(h, W2s[j * 2 + 1], o1);
    }
    ((float2*)out)[row] = make_float2(o0, o1);
}

extern "C" void kernel_launch(void* const* d_in, const int* in_sizes, int n_in,
                              void* d_out, int out_size, void* d_ws, size_t ws_size,
                              hipStream_t stream) {
    const float* x  = (const float*)d_in[0];
    const float* A1 = (const float*)d_in[1];
    const float* A2 = (const float*)d_in[2];
    const float* A3 = (const float*)d_in[3];
    const float* A4 = (const float*)d_in[4];
    const float* A5 = (const float*)d_in[5];
    const float* b1 = (const float*)d_in[6];
    const float* B1 = (const float*)d_in[7];
    const float* B2 = (const float*)d_in[8];
    const float* B3 = (const float*)d_in[9];
    const float* b2 = (const float*)d_in[10];
    float* out = (float*)d_out;

    float* W1 = (float*)d_ws;          // 25000 floats
    float* W2 = W1 + 25000;            // 100 floats

    build_w_kernel<<<1, 256, 0, stream>>>(A1, A2, A3, A4, A5, B1, B2, B3, W1, W2);
    tn_mlp_kernel<<<256, 256, 0, stream>>>(x, W1, W2, b1, b2, out);
}

// Round 3
// 263.983 us; speedup vs baseline: 1.3108x; 1.3108x over previous
//
#include <hip/hip_runtime.h>
#include <hip/hip_bf16.h>

// out = relu(x @ W1 + b1) @ W2 + b2
// W1 (500x50), W2 (50x2) precontracted from MPO cores into d_ws each call.

#define R 10

// ws layout (float offsets)
#define WS_W1   0        // 25000
#define WS_W2   25000    // 100
#define WS_L2C  25100    // 500
#define WS_C345 25600    // 5000

// ---------- build kernel 1: small contractions (1 block) -----------------
__global__ void build_small(const float* __restrict__ A1, const float* __restrict__ A2,
                            const float* __restrict__ A3, const float* __restrict__ A4,
                            const float* __restrict__ A5,
                            const float* __restrict__ B1, const float* __restrict__ B2,
                            const float* __restrict__ B3,
                            float* __restrict__ ws) {
    __shared__ float C45[200];   // ((r*5+l)*2+m)*2+x
    const int tid = threadIdx.x;
    float* L2cg  = ws + WS_L2C;   // ((i*5+j)*10+q)*5+v
    float* C345g = ws + WS_C345;  // ((((q*5+k)*5+l)*2+m)*5+w)*2+x
    float* W2g   = ws + WS_W2;    // f2*2+v

    // C45[r][l][m][x] = sum_s A4[((r*5+l)*10+s)*2+x] * A5[s*2+m]
    for (int t = tid; t < 200; t += 256) {
        int x_ = t & 1, m = (t >> 1) & 1, l = (t >> 2) % 5, r = t / 20;
        float s = 0.f;
        for (int ss = 0; ss < R; ++ss)
            s += A4[((r * 5 + l) * R + ss) * 2 + x_] * A5[ss * 2 + m];
        C45[t] = s;
    }
    // L2c[i][j][q][v] = sum_p A1[i*10+p] * A2[((p*5+j)*10+q)*5+v]
    for (int t = tid; t < 500; t += 256) {
        int v = t % 5, q = (t / 5) % R, j = (t / 50) % 5, i = t / 250;
        float s = 0.f;
        for (int p = 0; p < R; ++p)
            s += A1[i * R + p] * A2[((p * 5 + j) * R + q) * 5 + v];
        L2cg[t] = s;
    }
    // W2[f2*2+v] = sum_{p,q} B1[i*10+p]*B2[((p*5+j)*10+q)*2+v]*B3[q*5+k]
    for (int t = tid; t < 100; t += 256) {
        int v = t % 2, f2 = t / 2;
        int k = f2 % 5, j = (f2 / 5) % 5, i = f2 / 25;
        float s = 0.f;
        for (int p = 0; p < R; ++p) {
            float bp = B1[i * R + p];
            for (int q = 0; q < R; ++q)
                s += bp * B2[((p * 5 + j) * R + q) * 2 + v] * B3[q * 5 + k];
        }
        W2g[t] = s;
    }
    __syncthreads();
    // C345[q][k][l][m][w][x] = sum_r A3[((q*5+k)*10+r)*5+w] * C45[((r*5+l)*2+m)*2+x]
    for (int t = tid; t < 5000; t += 256) {
        int x_ = t % 2, w = (t / 2) % 5, m = (t / 10) % 2, l = (t / 20) % 5,
            k = (t / 100) % 5, q = t / 500;
        float s = 0.f;
        for (int r = 0; r < R; ++r)
            s += A3[((q * 5 + k) * R + r) * 5 + w] * C45[((r * 5 + l) * 2 + m) * 2 + x_];
        C345g[t] = s;
    }
}

// ---------- build kernel 2: W1[f*50+o] (98 blocks) -----------------------
__global__ void build_w1(float* __restrict__ ws) {
    const float* __restrict__ L2cg  = ws + WS_L2C;
    const float* __restrict__ C345g = ws + WS_C345;
    float* __restrict__ W1g = ws + WS_W1;
    int t = blockIdx.x * 256 + threadIdx.x;
    if (t >= 25000) return;
    int o = t % 50, f = t / 50;
    int x_ = o % 2, w = (o / 2) % 5, v = o / 10;
    int m = f % 2, l = (f / 2) % 5, k = (f / 10) % 5, j = (f / 50) % 5, i = f / 250;
    float s = 0.f;
#pragma unroll
    for (int q = 0; q < R; ++q)
        s += L2cg[((i * 5 + j) * R + q) * 5 + v] *
             C345g[((((q * 5 + k) * 5 + l) * 2 + m) * 5 + w) * 2 + x_];
    W1g[t] = s;
}

// ---------- main kernel ---------------------------------------------------
// Block: 256 thr = 64 rows x 4 k-quarters. 5 K-chunks of 100 staged in LDS.
// W1 rows read via wave-uniform scalar loads (kq = wave id).
__global__ __launch_bounds__(256) void tn_main(
    const float* __restrict__ x, const float* __restrict__ ws,
    const float* __restrict__ b1, const float* __restrict__ b2,
    float* __restrict__ out) {
    __shared__ float sm[64 * 101];   // x tile [64][101]; later partials [64][101]
    __shared__ float olds[64 * 4 * 2];
    __shared__ float w2s[100];
    __shared__ float b1s[50];

    const int tid = threadIdx.x;
    const int lane = tid & 63;
    const int kq = __builtin_amdgcn_readfirstlane(tid >> 6);  // wave id, uniform
    const long row0 = (long)blockIdx.x * 64;
    const float* __restrict__ W1 = ws + WS_W1;

    if (tid < 100) w2s[tid] = ws[WS_W2 + tid];
    if (tid < 50) b1s[tid] = b1[tid];

    float acc[50];
#pragma unroll
    for (int j = 0; j < 50; ++j) acc[j] = 0.f;

    for (int c = 0; c < 5; ++c) {
        __syncthreads();
        // stage x[row0..row0+63][c*100 .. +100) -> sm[r][k], pad 101, coalesced f4
        const float4* __restrict__ xg = (const float4*)x;  // row stride 125 f4
        for (int t = tid; t < 1600; t += 256) {
            int rr = t / 25, k4 = t - rr * 25;
            float4 v = xg[(row0 + rr) * 125 + c * 25 + k4];
            float* d = &sm[rr * 101 + k4 * 4];
            d[0] = v.x; d[1] = v.y; d[2] = v.z; d[3] = v.w;
        }
        __syncthreads();
        const float* wbase = W1 + (c * 100 + kq * 25) * 50;  // uniform -> s_load
        const float* xrow = &sm[lane * 101 + kq * 25];
#pragma unroll 1
        for (int kk = 0; kk < 25; ++kk) {
            float xv = xrow[kk];
            const float* wr = wbase + kk * 50;
#pragma unroll
            for (int j = 0; j < 50; ++j) acc[j] = fmaf(xv, wr[j], acc[j]);
        }
    }

    // cross-wave reduction of 4 partials, two j-halves through sm[64][101]
    const int rr = tid >> 2, s4 = tid & 3;
    float o0 = 0.f, o1 = 0.f;
#pragma unroll
    for (int h = 0; h < 2; ++h) {
        __syncthreads();
#pragma unroll
        for (int j2 = 0; j2 < 25; ++j2)
            sm[lane * 101 + j2 * 4 + kq] = acc[h * 25 + j2];
        __syncthreads();
        for (int j2 = s4; j2 < 25; j2 += 4) {
            int j = h * 25 + j2;
            float hsum = sm[rr * 101 + j2 * 4 + 0] + sm[rr * 101 + j2 * 4 + 1] +
                         sm[rr * 101 + j2 * 4 + 2] + sm[rr * 101 + j2 * 4 + 3] + b1s[j];
            hsum = fmaxf(hsum, 0.f);
            o0 = fmaf(hsum, w2s[2 * j], o0);
            o1 = fmaf(hsum, w2s[2 * j + 1], o1);
        }
    }
    olds[(rr * 4 + s4) * 2 + 0] = o0;
    olds[(rr * 4 + s4) * 2 + 1] = o1;
    __syncthreads();
    if (tid < 64) {
        float f0 = b2[0], f1 = b2[1];
#pragma unroll
        for (int s = 0; s < 4; ++s) {
            f0 += olds[(tid * 4 + s) * 2 + 0];
            f1 += olds[(tid * 4 + s) * 2 + 1];
        }
        ((float2*)out)[row0 + tid] = make_float2(f0, f1);
    }
}

extern "C" void kernel_launch(void* const* d_in, const int* in_sizes, int n_in,
                              void* d_out, int out_size, void* d_ws, size_t ws_size,
                              hipStream_t stream) {
    const float* x  = (const float*)d_in[0];
    const float* A1 = (const float*)d_in[1];
    const float* A2 = (const float*)d_in[2];
    const float* A3 = (const float*)d_in[3];
    const float* A4 = (const float*)d_in[4];
    const float* A5 = (const float*)d_in[5];
    const float* b1 = (const float*)d_in[6];
    const float* B1 = (const float*)d_in[7];
    const float* B2 = (const float*)d_in[8];
    const float* B3 = (const float*)d_in[9];
    const float* b2 = (const float*)d_in[10];
    float* out = (float*)d_out;
    float* ws = (float*)d_ws;

    build_small<<<1, 256, 0, stream>>>(A1, A2, A3, A4, A5, B1, B2, B3, ws);
    build_w1<<<98, 256, 0, stream>>>(ws);
    tn_main<<<1024, 256, 0, stream>>>(x, ws, b1, b2, out);
}